// Round 3
// baseline (429.183 us; speedup 1.0000x reference)
//
#include <hip/hip_runtime.h>
#include <math.h>

#define T_LEN 2048
#define B_SZ 2
#define EMB 1024
#define HEADS 16
#define HD 64
#define BH (B_SZ*HEADS)       // 32
#define R_ROWS (T_LEN*B_SZ)   // 4096

typedef unsigned short u16;
typedef __attribute__((ext_vector_type(8))) short bf16x8;
typedef __attribute__((ext_vector_type(4))) short bf16x4;
typedef __attribute__((ext_vector_type(4))) float f32x4;

#define MFMA32(a,b,c) __builtin_amdgcn_mfma_f32_16x16x32_bf16(a,b,c,0,0,0)
#if __has_builtin(__builtin_amdgcn_mfma_f32_16x16x16_bf16)
#define MFMA16(a,b,c) __builtin_amdgcn_mfma_f32_16x16x16_bf16(a,b,c,0,0,0)
#else
#define MFMA16(a,b,c) __builtin_amdgcn_mfma_f32_16x16x16bf16_1k(a,b,c,0,0,0)
#endif

__device__ __forceinline__ u16 f2bf(float f) {
    union { float f; unsigned int u; } v; v.f = f;
    unsigned int r = v.u + 0x7fffu + ((v.u >> 16) & 1u);
    return (u16)(r >> 16);
}
__device__ __forceinline__ float bf2f(u16 h) {
    union { unsigned int u; float f; } v; v.u = ((unsigned int)h) << 16;
    return v.f;
}
__device__ __forceinline__ ushort4 hi4(float4 x) {
    ushort4 u; u.x = f2bf(x.x); u.y = f2bf(x.y); u.z = f2bf(x.z); u.w = f2bf(x.w); return u;
}
__device__ __forceinline__ ushort4 lo4(float4 x, ushort4 h) {
    ushort4 u;
    u.x = f2bf(x.x - bf2f(h.x));
    u.y = f2bf(x.y - bf2f(h.y));
    u.z = f2bf(x.z - bf2f(h.z));
    u.w = f2bf(x.w - bf2f(h.w));
    return u;
}
// 2^x via HW v_exp_f32 (scores pre-scaled into log2 domain)
__device__ __forceinline__ float exp2f_fast(float x) {
#if __has_builtin(__builtin_amdgcn_exp2f)
    return __builtin_amdgcn_exp2f(x);
#else
    float r; asm("v_exp_f32 %0, %1" : "=v"(r) : "v"(x)); return r;
#endif
}
// 4x f32 -> packed bf16x4 via v_cvt_pk_bf16_f32 (RNE)
__device__ __forceinline__ bf16x4 pk_bf16x4(float a, float b, float c, float d) {
    union { unsigned int u[2]; bf16x4 v; } t;
    asm("v_cvt_pk_bf16_f32 %0, %1, %2" : "=v"(t.u[0]) : "v"(a), "v"(b));
    asm("v_cvt_pk_bf16_f32 %0, %1, %2" : "=v"(t.u[1]) : "v"(c), "v"(d));
    return t.v;
}
// async global->LDS, 16B/lane; lds base must be wave-uniform (lane lands at base + lane*16)
__device__ __forceinline__ void lds_cp16(u16* lds, const u16* g) {
    __builtin_amdgcn_global_load_lds(
        (const __attribute__((address_space(1))) unsigned int*)(const void*)g,
        (__attribute__((address_space(3))) unsigned int*)(void*)lds,
        16, 0, 0);
}

// ---------------- fp32 -> bf16 hi/lo split (grid-stride-free exact grid) ----
__global__ __launch_bounds__(256)
void conv_kernel(const float* __restrict__ src, u16* __restrict__ hi, u16* __restrict__ lo)
{
    size_t base = ((size_t)blockIdx.x*256 + threadIdx.x)*8;
    float4 a = *(const float4*)(src + base);
    float4 b = *(const float4*)(src + base + 4);
    ushort4 h0 = hi4(a), h1 = hi4(b);
    ushort4 l0 = lo4(a, h0), l1 = lo4(b, h1);
    *(ushort4*)(hi + base)     = h0;
    *(ushort4*)(hi + base + 4) = h1;
    *(ushort4*)(lo + base)     = l0;
    *(ushort4*)(lo + base + 4) = l1;
}

// ---------------- MFMA projection GEMM (compensated bf16) --------------------
// C = A·B^T + bias, both A,B stored [rows][K=1024] bf16 hi/lo. 128(M)x128(N)
// tile, BK=32, 256 thr = 4 waves in 2x2, each wave a 64x64 sub-tile (4x4 frags)
// -> 16 ds_read_b128 feed 48 MFMAs per K-step (reads/MFMA 0.33 vs 0.5 before;
// proj was LDS-read-BW-bound). 2-phase double-buffer, one barrier per K-step.
// mode 0: outF[r][n] fp32 (O-proj). mode 1: q/k head-major hi/lo bf16, *scale
//         (outLo may be null -> skip lo write). mode 2: A=W, B=X -> vT [bh][d][t].
__global__ __launch_bounds__(256)
void proj_mfma(const u16* __restrict__ Ahi, const u16* __restrict__ Alo,
               const u16* __restrict__ Bhi, const u16* __restrict__ Blo,
               const float* __restrict__ bias,
               float* __restrict__ outF, u16* __restrict__ outHi, u16* __restrict__ outLo,
               float scale, int mode)
{
    __shared__ __align__(16) u16 sAh[2][128*32];
    __shared__ __align__(16) u16 sAl[2][128*32];
    __shared__ __align__(16) u16 sBh[2][128*32];
    __shared__ __align__(16) u16 sBl[2][128*32];
    const int tid = threadIdx.x;
    const int w = tid >> 6, ln = tid & 63, lm = ln & 15, lq = ln >> 4;
    const int wm = w & 1, wn = w >> 1;
    const int m0 = blockIdx.x * 128, n0 = blockIdx.y * 128;
    const int K = 1024;
    const int ar = ln >> 2;      // staging: row within 16-row chunk
    const int ac = ln & 3;       // staging: 16B chunk within 64B row

    f32x4 acc[4][4];
#pragma unroll
    for (int i = 0; i < 4; ++i)
#pragma unroll
        for (int j = 0; j < 4; ++j) acc[i][j] = (f32x4){0.f,0.f,0.f,0.f};

    auto stage = [&](int p, int k0) {
#pragma unroll
        for (int i = 0; i < 2; ++i) {
            int ch = w*2 + i;
            int r = ch*16 + ar;
            int c = ac ^ ((r >> 1) & 3);
            size_t gA = (size_t)(m0 + r)*K + k0 + c*8;
            size_t gB = (size_t)(n0 + r)*K + k0 + c*8;
            lds_cp16(&sAh[p][ch*512], Ahi + gA);
            lds_cp16(&sAl[p][ch*512], Alo + gA);
            lds_cp16(&sBh[p][ch*512], Bhi + gB);
            lds_cp16(&sBl[p][ch*512], Blo + gB);
        }
    };

    stage(0, 0);
    int cur = 0;
    for (int k0 = 0; k0 < 1024; k0 += 32) {
        __syncthreads();                       // buf[cur] staged + prev reads done
        if (k0 + 32 < 1024) stage(cur ^ 1, k0 + 32);   // prefetch under compute

        bf16x8 afh[4], afl[4];
#pragma unroll
        for (int i = 0; i < 4; ++i) {
            int row = wm*64 + i*16 + lm;
            int off = row*32 + (lq ^ ((row >> 1) & 3))*8;
            afh[i] = *(const bf16x8*)&sAh[cur][off];
            afl[i] = *(const bf16x8*)&sAl[cur][off];
        }
#pragma unroll
        for (int j = 0; j < 4; ++j) {
            int row = wn*64 + j*16 + lm;
            int off = row*32 + (lq ^ ((row >> 1) & 3))*8;
            bf16x8 bfh = *(const bf16x8*)&sBh[cur][off];
            bf16x8 bfl = *(const bf16x8*)&sBl[cur][off];
#pragma unroll
            for (int i = 0; i < 4; ++i) {
                f32x4 a = acc[i][j];
                a = MFMA32(afh[i], bfl, a);
                a = MFMA32(afl[i], bfh, a);
                a = MFMA32(afh[i], bfh, a);
                acc[i][j] = a;
            }
        }
        cur ^= 1;
    }

    if (mode == 0) {
#pragma unroll
        for (int j = 0; j < 4; ++j) {
            float bv = bias[n0 + wn*64 + j*16 + lm];
#pragma unroll
            for (int i = 0; i < 4; ++i)
#pragma unroll
                for (int r = 0; r < 4; ++r) {
                    int gm = m0 + wm*64 + i*16 + lq*4 + r;
                    outF[(size_t)gm*EMB + n0 + wn*64 + j*16 + lm] = acc[i][j][r] + bv;
                }
        }
    } else if (mode == 1) {
        const int h = (n0 >> 6) + wn;          // wave's 64-wide n-range = one head
#pragma unroll
        for (int j = 0; j < 4; ++j) {
            float bv = bias[n0 + wn*64 + j*16 + lm];
            int d = j*16 + lm;
#pragma unroll
            for (int i = 0; i < 4; ++i)
#pragma unroll
                for (int r = 0; r < 4; ++r) {
                    int gm = m0 + wm*64 + i*16 + lq*4 + r;
                    int t = gm >> 1, bb = gm & 1;
                    float val = (acc[i][j][r] + bv) * scale;
                    u16 hv = f2bf(val);
                    size_t o = ((size_t)(bb*HEADS + h)*T_LEN + t)*HD + d;
                    outHi[o] = hv;
                    if (outLo) outLo[o] = f2bf(val - bf2f(hv));
                }
        }
    } else {
#pragma unroll
        for (int i = 0; i < 4; ++i)
#pragma unroll
            for (int r = 0; r < 4; ++r) {
                int gm = m0 + wm*64 + i*16 + lq*4 + r;   // W row = out channel
                int h = gm >> 6, d = gm & 63;
                float bv = bias[gm];
#pragma unroll
                for (int j = 0; j < 4; ++j) {
                    int gn = n0 + wn*64 + j*16 + lm;     // X row = token
                    int t = gn >> 1, bb = gn & 1;
                    outHi[((size_t)(bb*HEADS + h)*HD + d)*T_LEN + t] = f2bf(acc[i][j][r] + bv);
                }
            }
    }
}

// ---------------- MFMA flash attention -------------------
// S^T = K·Q^T so the score C-frag is directly the PV A-frag. Scores in log2
// domain. K-lo terms DROPPED (score err ~3e-3 rms in log2 units -> negligible
// after exp2; K is plain bf16 now): QK is 4 MFMA32/frag-pair, no Klo array.
// 64 t per block, 256 thr = 4 waves x 16 rows; grid 1024 -> 4 blocks/CU
// (LDS 32KB) = 50% occupancy. 2-phase K/V double-buffer; T13 defer-max.
__global__ __launch_bounds__(256)
void flash_kernel(const u16* __restrict__ qHi, const u16* __restrict__ qLo,
                  const u16* __restrict__ kHi, const u16* __restrict__ vT,
                  u16* __restrict__ attnHi, u16* __restrict__ attnLo,
                  float* __restrict__ mbuf, float* __restrict__ lbuf)
{
    __shared__ __align__(16) u16 Khi[2][64*64];
    __shared__ __align__(16) u16 Vts[2][64*64];   // logical [d][s]
    const int tid = threadIdx.x;
    const int w = tid >> 6, ln = tid & 63, lm = ln & 15, lq = ln >> 4;
    const int bh = blockIdx.y;
    const int t0 = blockIdx.x * 64;
    const int b = bh >> 4, hh = bh & 15;
    const int sr = ln >> 3, scc = ln & 7;      // staging decode (128B rows)

    bf16x8 qfhi[2], qflo[2];
    {
        size_t qo = ((size_t)bh*T_LEN + t0 + w*16 + lm)*HD;
#pragma unroll
        for (int f = 0; f < 2; ++f) {
            qfhi[f] = *(const bf16x8*)(qHi + qo + f*32 + lq*8);
            qflo[f] = *(const bf16x8*)(qLo + qo + f*32 + lq*8);
        }
    }

    f32x4 O[4];
    float m_t = -INFINITY, l_t = 0.f;
#pragma unroll
    for (int dt = 0; dt < 4; ++dt) O[dt] = (f32x4){0.f,0.f,0.f,0.f};

    auto stage = [&](int p, int s0) {
#pragma unroll
        for (int i = 0; i < 2; ++i) {
            int ch = w*2 + i;
            int r = ch*8 + sr;
            int c = scc ^ (r & 7);
            lds_cp16(&Khi[p][ch*512], kHi + ((size_t)bh*T_LEN + s0 + r)*HD + c*8);
            lds_cp16(&Vts[p][ch*512], vT  + ((size_t)bh*HD + r)*T_LEN + s0 + c*8);
        }
    };

    stage(0, 0);
    int cur = 0;
    for (int s0 = 0; s0 < T_LEN; s0 += 64) {
        __syncthreads();                       // drains vmcnt: buf[cur] ready
        if (s0 + 64 < T_LEN) stage(cur ^ 1, s0 + 64);  // prefetch overlaps compute

        const u16* __restrict__ KH = Khi[cur];
        const u16* __restrict__ VS = Vts[cur];

        f32x4 S[4];
#pragma unroll
        for (int ms = 0; ms < 4; ++ms) {
            const int kr = ms*16 + lm;
            const int sw = kr & 7;
            const u16* rowH = &KH[kr*64];
            bf16x8 ah0 = *(const bf16x8*)(rowH + ((lq    ) ^ sw)*8);
            bf16x8 ah1 = *(const bf16x8*)(rowH + ((lq + 4) ^ sw)*8);
            __builtin_amdgcn_s_setprio(1);
            f32x4 s4 = {0.f,0.f,0.f,0.f};
            s4 = MFMA32(ah0, qflo[0], s4);
            s4 = MFMA32(ah1, qflo[1], s4);
            s4 = MFMA32(ah0, qfhi[0], s4);
            s4 = MFMA32(ah1, qfhi[1], s4);
            __builtin_amdgcn_s_setprio(0);
            S[ms] = s4;
        }

        bf16x4 P[4];
        {
            float mx = fmaxf(fmaxf(S[0][0], S[0][1]), fmaxf(S[0][2], S[0][3]));
#pragma unroll
            for (int ms = 1; ms < 4; ++ms)
                mx = fmaxf(mx, fmaxf(fmaxf(S[ms][0], S[ms][1]),
                                     fmaxf(S[ms][2], S[ms][3])));
            mx = fmaxf(mx, __shfl_xor(mx, 16));
            mx = fmaxf(mx, __shfl_xor(mx, 32));
            if (__any(mx > m_t + 8.0f)) {          // T13: rescale only on growth
                float mnew = fmaxf(m_t, mx);
                float alpha = exp2f_fast(m_t - mnew);
                m_t = mnew;
                l_t *= alpha;
                f32x4 av;
#pragma unroll
                for (int r = 0; r < 4; ++r) av[r] = __shfl(alpha, lq*4 + r);
#pragma unroll
                for (int dt = 0; dt < 4; ++dt) O[dt] *= av;
            }
            const float mn = m_t;
            float rs = 0.f;
#pragma unroll
            for (int ms = 0; ms < 4; ++ms) {
                float p0 = exp2f_fast(S[ms][0]-mn);
                float p1 = exp2f_fast(S[ms][1]-mn);
                float p2 = exp2f_fast(S[ms][2]-mn);
                float p3 = exp2f_fast(S[ms][3]-mn);
                rs += (p0+p1)+(p2+p3);
                P[ms] = pk_bf16x4(p0, p1, p2, p3);
            }
            rs += __shfl_xor(rs, 16);
            rs += __shfl_xor(rs, 32);
            l_t += rs;
        }

        __builtin_amdgcn_s_setprio(1);
#pragma unroll
        for (int dt = 0; dt < 4; ++dt) {
            const int d = dt*16 + lm;
            const int dw = d & 7;
#pragma unroll
            for (int ms = 0; ms < 4; ++ms) {
                bf16x4 vf = *(const bf16x4*)&VS[d*64 + ((2*ms + (lq>>1)) ^ dw)*8 + (lq&1)*4];
                O[dt] = MFMA16(P[ms], vf, O[dt]);
            }
        }
        __builtin_amdgcn_s_setprio(0);
        cur ^= 1;
    }

    {
        float inv = 1.0f / l_t;
        f32x4 iv;
#pragma unroll
        for (int r = 0; r < 4; ++r) iv[r] = __shfl(inv, lq*4 + r);
        int tbase = t0 + w*16;
        if (lq == 0) {
            mbuf[(size_t)bh*T_LEN + tbase + lm] = m_t;
            lbuf[(size_t)bh*T_LEN + tbase + lm] = l_t;
        }
#pragma unroll
        for (int dt = 0; dt < 4; ++dt)
#pragma unroll
            for (int r = 0; r < 4; ++r) {
                int t = tbase + lq*4 + r;
                float val = O[dt][r] * iv[r];
                u16 hv = f2bf(val);
                u16 lv = f2bf(val - bf2f(hv));
                size_t o = ((size_t)t*B_SZ + b)*EMB + hh*HD + dt*16 + lm;
                attnHi[o] = hv; attnLo[o] = lv;
            }
    }
}

// ---------------- avg weights: MFMA recompute S^T, apply saved (m,l) ---------
// Same dropped-K-lo 4-MFMA score (IDENTICAL term set & order as flash ->
// consistent with saved m,l). 512 thr = 8 waves x 16 t-rows; K-hi only,
// double-buffered across heads (32KB LDS -> 2 blocks/CU = 50% occupancy).
__global__ __launch_bounds__(512)
void avg_kernel(const u16* __restrict__ qHi, const u16* __restrict__ qLo,
                const u16* __restrict__ kHi,
                const float* __restrict__ mbuf, const float* __restrict__ lbuf,
                float* __restrict__ avg)
{
    __shared__ __align__(16) u16 Khi[2][128*64];
    const int tid = threadIdx.x;
    const int w = tid >> 6, ln = tid & 63, lm = ln & 15, lq = ln >> 4;
    const int s0 = blockIdx.x * 128;
    const int t0 = blockIdx.y * 128;
    const int b  = blockIdx.z;
    const int sr = ln >> 3, scc = ln & 7;
    f32x4 acc[8];
#pragma unroll
    for (int ms = 0; ms < 8; ++ms) acc[ms] = (f32x4){0.f,0.f,0.f,0.f};

    auto stage = [&](int p, int h) {
        const int bhh = b*HEADS + h;
#pragma unroll
        for (int i = 0; i < 2; ++i) {
            int ch = w*2 + i;            // 16 chunks over 8 waves
            int r = ch*8 + sr;
            int c = scc ^ (r & 7);
            lds_cp16(&Khi[p][ch*512], kHi + ((size_t)bhh*T_LEN + s0 + r)*HD + c*8);
        }
    };

    stage(0, 0);
    int cur = 0;
    const int t = t0 + w*16 + lm;
    for (int h = 0; h < HEADS; ++h) {
        const int bh = b*HEADS + h;
        // q/m/l loads issued BEFORE the barrier: latency overlaps the drain.
        bf16x8 qfh[2], qfl[2];
        size_t qo = ((size_t)bh*T_LEN + t)*HD;
#pragma unroll
        for (int f = 0; f < 2; ++f) {
            qfh[f] = *(const bf16x8*)(qHi + qo + f*32 + lq*8);
            qfl[f] = *(const bf16x8*)(qLo + qo + f*32 + lq*8);
        }
        float mv = mbuf[(size_t)bh*T_LEN + t];
        float lv = 1.0f / lbuf[(size_t)bh*T_LEN + t];
        __syncthreads();                       // buf[cur] staged + prev reads done
        if (h + 1 < HEADS) stage(cur ^ 1, h + 1);   // prefetch next head

        const u16* __restrict__ KH = Khi[cur];
#pragma unroll
        for (int ms = 0; ms < 8; ++ms) {
            const int kr = ms*16 + lm;
            const int sw = kr & 7;
            const u16* rowH = &KH[kr*64];
            bf16x8 ah0 = *(const bf16x8*)(rowH + ((lq    ) ^ sw)*8);
            bf16x8 ah1 = *(const bf16x8*)(rowH + ((lq + 4) ^ sw)*8);
            f32x4 s4 = {0.f,0.f,0.f,0.f};
            s4 = MFMA32(ah0, qfl[0], s4);
            s4 = MFMA32(ah1, qfl[1], s4);
            s4 = MFMA32(ah0, qfh[0], s4);
            s4 = MFMA32(ah1, qfh[1], s4);
            f32x4 a = acc[ms];
            a[0] += exp2f_fast(s4[0]-mv)*lv;
            a[1] += exp2f_fast(s4[1]-mv)*lv;
            a[2] += exp2f_fast(s4[2]-mv)*lv;
            a[3] += exp2f_fast(s4[3]-mv)*lv;
            acc[ms] = a;
        }
        cur ^= 1;
    }
    const float sc = 1.0f / HEADS;
#pragma unroll
    for (int ms = 0; ms < 8; ++ms) {
        float4 v;
        v.x = acc[ms][0]*sc; v.y = acc[ms][1]*sc;
        v.z = acc[ms][2]*sc; v.w = acc[ms][3]*sc;
        *(float4*)(avg + ((size_t)b*T_LEN + t)*T_LEN + s0 + ms*16 + lq*4) = v;
    }
}

extern "C" void kernel_launch(void* const* d_in, const int* in_sizes, int n_in,
                              void* d_out, int out_size, void* d_ws, size_t ws_size,
                              hipStream_t stream)
{
    const float* query = (const float*)d_in[0];
    const float* key   = (const float*)d_in[1];
    const float* value = (const float*)d_in[2];
    const float* Wq = (const float*)d_in[3];
    const float* bq = (const float*)d_in[4];
    const float* Wk = (const float*)d_in[5];
    const float* bk = (const float*)d_in[6];
    const float* Wv = (const float*)d_in[7];
    const float* bv = (const float*)d_in[8];
    const float* Wo = (const float*)d_in[9];
    const float* bo = (const float*)d_in[10];

    float* out = (float*)d_out;                  // [T,B,E]
    float* avg = out + (size_t)R_ROWS*EMB;       // [B,T,S]

    const size_t NX = (size_t)R_ROWS*EMB;        // 4194304
    const size_t NW = (size_t)EMB*EMB;           // 1048576
    u16* wsu = (u16*)d_ws;
    u16* cHi  = wsu;            u16* cLo  = cHi + NX;     // conv scratch; later attnHi/Lo
    u16* WqHi = cLo + NX;       u16* WqLo = WqHi + NW;
    u16* WkHi = WqLo + NW;      u16* WkLo = WkHi + NW;
    u16* WvHi = WkLo + NW;      u16* WvLo = WvHi + NW;
    u16* WoHi = WvLo + NW;      u16* WoLo = WoHi + NW;
    u16* qHi  = WoLo + NW;      u16* qLo  = qHi + NX;     // head-major [bh][t][d]
    u16* kHi  = qLo + NX;       u16* kLo  = kHi + NX;     // kLo slot unused now
    u16* vT   = kLo + NX;                                  // [bh][d][t]
    float* mb = (float*)(vT + NX);
    float* lb = mb + (size_t)BH*T_LEN;

    // HEAD_DIM^-0.5 * log2(e): scores land in log2 domain -> bare v_exp_f32.
    const float qscale = 0.125f * 1.44269504088896340736f;

    // weight hi/lo splits
    conv_kernel<<<NW/2048, 256, 0, stream>>>(Wq, WqHi, WqLo);
    conv_kernel<<<NW/2048, 256, 0, stream>>>(Wk, WkHi, WkLo);
    conv_kernel<<<NW/2048, 256, 0, stream>>>(Wv, WvHi, WvLo);
    conv_kernel<<<NW/2048, 256, 0, stream>>>(Wo, WoHi, WoLo);

    dim3 gP(R_ROWS/128, EMB/128);      // (32,8)  modes 0/1
    dim3 gPv(EMB/128, R_ROWS/128);     // (8,32)  mode 2

    conv_kernel<<<NX/2048, 256, 0, stream>>>(query, cHi, cLo);
    proj_mfma<<<gP, 256, 0, stream>>>(cHi, cLo, WqHi, WqLo, bq, nullptr, qHi, qLo, qscale, 1);
    conv_kernel<<<NX/2048, 256, 0, stream>>>(key, cHi, cLo);
    proj_mfma<<<gP, 256, 0, stream>>>(cHi, cLo, WkHi, WkLo, bk, nullptr, kHi, nullptr, 1.0f, 1);
    conv_kernel<<<NX/2048, 256, 0, stream>>>(value, cHi, cLo);
    proj_mfma<<<gPv, 256, 0, stream>>>(WvHi, WvLo, cHi, cLo, bv, nullptr, vT, nullptr, 1.0f, 2);

    flash_kernel<<<dim3(T_LEN/64, BH), 256, 0, stream>>>(qHi, qLo, kHi, vT,
                                                         cHi, cLo, mb, lb);
    proj_mfma<<<gP, 256, 0, stream>>>(cHi, cLo, WoHi, WoLo, bo, out, nullptr, nullptr, 1.0f, 0);
    avg_kernel<<<dim3(T_LEN/128, T_LEN/128, B_SZ), 512, 0, stream>>>(qHi, qLo, kHi, mb, lb, avg);
}

// Round 4
// 391.352 us; speedup vs baseline: 1.0967x; 1.0967x over previous
//
#include <hip/hip_runtime.h>
#include <math.h>

#define T_LEN 2048
#define B_SZ 2
#define EMB 1024
#define HEADS 16
#define HD 64
#define BH (B_SZ*HEADS)       // 32
#define R_ROWS (T_LEN*B_SZ)   // 4096

typedef unsigned short u16;
typedef __attribute__((ext_vector_type(8))) short bf16x8;
typedef __attribute__((ext_vector_type(4))) short bf16x4;
typedef __attribute__((ext_vector_type(4))) float f32x4;

#define MFMA32(a,b,c) __builtin_amdgcn_mfma_f32_16x16x32_bf16(a,b,c,0,0,0)
#if __has_builtin(__builtin_amdgcn_mfma_f32_16x16x16_bf16)
#define MFMA16(a,b,c) __builtin_amdgcn_mfma_f32_16x16x16_bf16(a,b,c,0,0,0)
#else
#define MFMA16(a,b,c) __builtin_amdgcn_mfma_f32_16x16x16bf16_1k(a,b,c,0,0,0)
#endif

__device__ __forceinline__ u16 f2bf(float f) {
    union { float f; unsigned int u; } v; v.f = f;
    unsigned int r = v.u + 0x7fffu + ((v.u >> 16) & 1u);
    return (u16)(r >> 16);
}
__device__ __forceinline__ float bf2f(u16 h) {
    union { unsigned int u; float f; } v; v.u = ((unsigned int)h) << 16;
    return v.f;
}
__device__ __forceinline__ ushort4 hi4(float4 x) {
    ushort4 u; u.x = f2bf(x.x); u.y = f2bf(x.y); u.z = f2bf(x.z); u.w = f2bf(x.w); return u;
}
__device__ __forceinline__ ushort4 lo4(float4 x, ushort4 h) {
    ushort4 u;
    u.x = f2bf(x.x - bf2f(h.x));
    u.y = f2bf(x.y - bf2f(h.y));
    u.z = f2bf(x.z - bf2f(h.z));
    u.w = f2bf(x.w - bf2f(h.w));
    return u;
}
// 2^x via HW v_exp_f32 (scores pre-scaled into log2 domain)
__device__ __forceinline__ float exp2f_fast(float x) {
#if __has_builtin(__builtin_amdgcn_exp2f)
    return __builtin_amdgcn_exp2f(x);
#else
    float r; asm("v_exp_f32 %0, %1" : "=v"(r) : "v"(x)); return r;
#endif
}
// 4x f32 -> packed bf16x4 via v_cvt_pk_bf16_f32 (RNE)
__device__ __forceinline__ bf16x4 pk_bf16x4(float a, float b, float c, float d) {
    union { unsigned int u[2]; bf16x4 v; } t;
    asm("v_cvt_pk_bf16_f32 %0, %1, %2" : "=v"(t.u[0]) : "v"(a), "v"(b));
    asm("v_cvt_pk_bf16_f32 %0, %1, %2" : "=v"(t.u[1]) : "v"(c), "v"(d));
    return t.v;
}
// async global->LDS, 16B/lane; lds base must be wave-uniform (lane lands at base + lane*16)
__device__ __forceinline__ void lds_cp16(u16* lds, const u16* g) {
    __builtin_amdgcn_global_load_lds(
        (const __attribute__((address_space(1))) unsigned int*)(const void*)g,
        (__attribute__((address_space(3))) unsigned int*)(void*)lds,
        16, 0, 0);
}

// ---------------- fp32 -> bf16 hi/lo split (grid-stride-free exact grid) ----
__global__ __launch_bounds__(256)
void conv_kernel(const float* __restrict__ src, u16* __restrict__ hi, u16* __restrict__ lo)
{
    size_t base = ((size_t)blockIdx.x*256 + threadIdx.x)*8;
    float4 a = *(const float4*)(src + base);
    float4 b = *(const float4*)(src + base + 4);
    ushort4 h0 = hi4(a), h1 = hi4(b);
    ushort4 l0 = lo4(a, h0), l1 = lo4(b, h1);
    *(ushort4*)(hi + base)     = h0;
    *(ushort4*)(hi + base + 4) = h1;
    *(ushort4*)(lo + base)     = l0;
    *(ushort4*)(lo + base + 4) = l1;
}

// ---------------- MFMA projection GEMM (compensated bf16) --------------------
// C = A·B^T + bias, both A,B stored [rows][K=1024] bf16 hi/lo. 128(M)x64(N)
// tile, BK=32, 512 thr = 8 waves in 4(m)x2(n), each wave 32x32 (2x2 frags).
// proj is latency/barrier-bound, not LDS-BW-bound (aggregate LDS floor ~15us
// vs ~60us measured at 4 waves) -> occupancy is the lever: 2 blocks/CU x 8
// waves = 16 waves/CU (50%), 2x round-2, 4x round-3's 128x128 config.
// 2-phase double-buffer, one barrier per K-step; 3 lds_cp16 per thread.
// mode 0: outF[r][n] fp32 (O-proj). mode 1: q/k head-major hi/lo bf16, *scale
//         (outLo null -> skip lo write). mode 2: A=W, B=X -> vT bf16 [bh][d][t].
__global__ __launch_bounds__(512)
void proj_mfma(const u16* __restrict__ Ahi, const u16* __restrict__ Alo,
               const u16* __restrict__ Bhi, const u16* __restrict__ Blo,
               const float* __restrict__ bias,
               float* __restrict__ outF, u16* __restrict__ outHi, u16* __restrict__ outLo,
               float scale, int mode)
{
    __shared__ __align__(16) u16 sAh[2][128*32];
    __shared__ __align__(16) u16 sAl[2][128*32];
    __shared__ __align__(16) u16 sBh[2][64*32];
    __shared__ __align__(16) u16 sBl[2][64*32];
    const int tid = threadIdx.x;
    const int w = tid >> 6, ln = tid & 63, lm = ln & 15, lq = ln >> 4;
    const int wm = w & 3, wn = w >> 2;       // 4(m) x 2(n) waves, 32x32 each
    const int m0 = blockIdx.x * 128, n0 = blockIdx.y * 64;
    const int K = 1024;
    const int ar = ln >> 2;      // staging: row within 16-row chunk
    const int ac = ln & 3;       // staging: 16B chunk within 64B row

    f32x4 acc[2][2];
#pragma unroll
    for (int i = 0; i < 2; ++i)
#pragma unroll
        for (int j = 0; j < 2; ++j) acc[i][j] = (f32x4){0.f,0.f,0.f,0.f};

    auto stage = [&](int p, int k0) {
        {   // A chunk w (16 rows of the 128-row tile), hi + lo
            int r = w*16 + ar;
            int c = ac ^ ((r >> 1) & 3);
            size_t g = (size_t)(m0 + r)*K + k0 + c*8;
            lds_cp16(&sAh[p][w*512], Ahi + g);
            lds_cp16(&sAl[p][w*512], Alo + g);
        }
        {   // B chunk (w&3): waves 0-3 stage hi, waves 4-7 stage lo
            int ch = w & 3;
            int r = ch*16 + ar;
            int c = ac ^ ((r >> 1) & 3);
            size_t g = (size_t)(n0 + r)*K + k0 + c*8;
            if (w < 4) lds_cp16(&sBh[p][ch*512], Bhi + g);
            else       lds_cp16(&sBl[p][ch*512], Blo + g);
        }
    };

    stage(0, 0);
    int cur = 0;
    for (int k0 = 0; k0 < 1024; k0 += 32) {
        __syncthreads();                       // buf[cur] staged + prev reads done
        if (k0 + 32 < 1024) stage(cur ^ 1, k0 + 32);   // prefetch under compute

        bf16x8 afh[2], afl[2], bfh[2], bfl[2];
#pragma unroll
        for (int i = 0; i < 2; ++i) {
            int row = wm*32 + i*16 + lm;
            int off = row*32 + (lq ^ ((row >> 1) & 3))*8;
            afh[i] = *(const bf16x8*)&sAh[cur][off];
            afl[i] = *(const bf16x8*)&sAl[cur][off];
        }
#pragma unroll
        for (int j = 0; j < 2; ++j) {
            int row = wn*32 + j*16 + lm;
            int off = row*32 + (lq ^ ((row >> 1) & 3))*8;
            bfh[j] = *(const bf16x8*)&sBh[cur][off];
            bfl[j] = *(const bf16x8*)&sBl[cur][off];
        }
#pragma unroll
        for (int i = 0; i < 2; ++i)
#pragma unroll
            for (int j = 0; j < 2; ++j) {
                f32x4 a = acc[i][j];
                a = MFMA32(afh[i], bfl[j], a);
                a = MFMA32(afl[i], bfh[j], a);
                a = MFMA32(afh[i], bfh[j], a);
                acc[i][j] = a;
            }
        cur ^= 1;
    }

    if (mode == 0) {
#pragma unroll
        for (int j = 0; j < 2; ++j) {
            float bv = bias[n0 + wn*32 + j*16 + lm];
#pragma unroll
            for (int i = 0; i < 2; ++i)
#pragma unroll
                for (int r = 0; r < 4; ++r) {
                    int gm = m0 + wm*32 + i*16 + lq*4 + r;
                    outF[(size_t)gm*EMB + n0 + wn*32 + j*16 + lm] = acc[i][j][r] + bv;
                }
        }
    } else if (mode == 1) {
        const int h = n0 >> 6;                 // 64-wide n-tile = one head
#pragma unroll
        for (int j = 0; j < 2; ++j) {
            float bv = bias[n0 + wn*32 + j*16 + lm];
            int d = wn*32 + j*16 + lm;
#pragma unroll
            for (int i = 0; i < 2; ++i)
#pragma unroll
                for (int r = 0; r < 4; ++r) {
                    int gm = m0 + wm*32 + i*16 + lq*4 + r;
                    int t = gm >> 1, bb = gm & 1;
                    float val = (acc[i][j][r] + bv) * scale;
                    u16 hv = f2bf(val);
                    size_t o = ((size_t)(bb*HEADS + h)*T_LEN + t)*HD + d;
                    outHi[o] = hv;
                    if (outLo) outLo[o] = f2bf(val - bf2f(hv));
                }
        }
    } else {
#pragma unroll
        for (int i = 0; i < 2; ++i)
#pragma unroll
            for (int r = 0; r < 4; ++r) {
                int gm = m0 + wm*32 + i*16 + lq*4 + r;   // W row = out channel
                int h = gm >> 6, d = gm & 63;
                float bv = bias[gm];
#pragma unroll
                for (int j = 0; j < 2; ++j) {
                    int gn = n0 + wn*32 + j*16 + lm;     // X row = token
                    int t = gn >> 1, bb = gn & 1;
                    outHi[((size_t)(bb*HEADS + h)*HD + d)*T_LEN + t] = f2bf(acc[i][j][r] + bv);
                }
            }
    }
}

// ---------------- MFMA flash attention -------------------
// S^T = K·Q^T so the score C-frag is directly the PV A-frag. Scores in log2
// domain. K-lo terms DROPPED (score err ~3e-3 rms in log2 units -> negligible
// after exp2; K is plain bf16 now): QK is 4 MFMA32/frag-pair, no Klo array.
// 64 t per block, 256 thr = 4 waves x 16 rows; grid 1024 -> 4 blocks/CU
// (LDS 32KB) = 50% occupancy. 2-phase K/V double-buffer; T13 defer-max.
__global__ __launch_bounds__(256)
void flash_kernel(const u16* __restrict__ qHi, const u16* __restrict__ qLo,
                  const u16* __restrict__ kHi, const u16* __restrict__ vT,
                  u16* __restrict__ attnHi, u16* __restrict__ attnLo,
                  float* __restrict__ mbuf, float* __restrict__ lbuf)
{
    __shared__ __align__(16) u16 Khi[2][64*64];
    __shared__ __align__(16) u16 Vts[2][64*64];   // logical [d][s]
    const int tid = threadIdx.x;
    const int w = tid >> 6, ln = tid & 63, lm = ln & 15, lq = ln >> 4;
    const int bh = blockIdx.y;
    const int t0 = blockIdx.x * 64;
    const int b = bh >> 4, hh = bh & 15;
    const int sr = ln >> 3, scc = ln & 7;      // staging decode (128B rows)

    bf16x8 qfhi[2], qflo[2];
    {
        size_t qo = ((size_t)bh*T_LEN + t0 + w*16 + lm)*HD;
#pragma unroll
        for (int f = 0; f < 2; ++f) {
            qfhi[f] = *(const bf16x8*)(qHi + qo + f*32 + lq*8);
            qflo[f] = *(const bf16x8*)(qLo + qo + f*32 + lq*8);
        }
    }

    f32x4 O[4];
    float m_t = -INFINITY, l_t = 0.f;
#pragma unroll
    for (int dt = 0; dt < 4; ++dt) O[dt] = (f32x4){0.f,0.f,0.f,0.f};

    auto stage = [&](int p, int s0) {
#pragma unroll
        for (int i = 0; i < 2; ++i) {
            int ch = w*2 + i;
            int r = ch*8 + sr;
            int c = scc ^ (r & 7);
            lds_cp16(&Khi[p][ch*512], kHi + ((size_t)bh*T_LEN + s0 + r)*HD + c*8);
            lds_cp16(&Vts[p][ch*512], vT  + ((size_t)bh*HD + r)*T_LEN + s0 + c*8);
        }
    };

    stage(0, 0);
    int cur = 0;
    for (int s0 = 0; s0 < T_LEN; s0 += 64) {
        __syncthreads();                       // drains vmcnt: buf[cur] ready
        if (s0 + 64 < T_LEN) stage(cur ^ 1, s0 + 64);  // prefetch overlaps compute

        const u16* __restrict__ KH = Khi[cur];
        const u16* __restrict__ VS = Vts[cur];

        f32x4 S[4];
#pragma unroll
        for (int ms = 0; ms < 4; ++ms) {
            const int kr = ms*16 + lm;
            const int sw = kr & 7;
            const u16* rowH = &KH[kr*64];
            bf16x8 ah0 = *(const bf16x8*)(rowH + ((lq    ) ^ sw)*8);
            bf16x8 ah1 = *(const bf16x8*)(rowH + ((lq + 4) ^ sw)*8);
            __builtin_amdgcn_s_setprio(1);
            f32x4 s4 = {0.f,0.f,0.f,0.f};
            s4 = MFMA32(ah0, qflo[0], s4);
            s4 = MFMA32(ah1, qflo[1], s4);
            s4 = MFMA32(ah0, qfhi[0], s4);
            s4 = MFMA32(ah1, qfhi[1], s4);
            __builtin_amdgcn_s_setprio(0);
            S[ms] = s4;
        }

        bf16x4 P[4];
        {
            float mx = fmaxf(fmaxf(S[0][0], S[0][1]), fmaxf(S[0][2], S[0][3]));
#pragma unroll
            for (int ms = 1; ms < 4; ++ms)
                mx = fmaxf(mx, fmaxf(fmaxf(S[ms][0], S[ms][1]),
                                     fmaxf(S[ms][2], S[ms][3])));
            mx = fmaxf(mx, __shfl_xor(mx, 16));
            mx = fmaxf(mx, __shfl_xor(mx, 32));
            if (__any(mx > m_t + 8.0f)) {          // T13: rescale only on growth
                float mnew = fmaxf(m_t, mx);
                float alpha = exp2f_fast(m_t - mnew);
                m_t = mnew;
                l_t *= alpha;
                f32x4 av;
#pragma unroll
                for (int r = 0; r < 4; ++r) av[r] = __shfl(alpha, lq*4 + r);
#pragma unroll
                for (int dt = 0; dt < 4; ++dt) O[dt] *= av;
            }
            const float mn = m_t;
            float rs = 0.f;
#pragma unroll
            for (int ms = 0; ms < 4; ++ms) {
                float p0 = exp2f_fast(S[ms][0]-mn);
                float p1 = exp2f_fast(S[ms][1]-mn);
                float p2 = exp2f_fast(S[ms][2]-mn);
                float p3 = exp2f_fast(S[ms][3]-mn);
                rs += (p0+p1)+(p2+p3);
                P[ms] = pk_bf16x4(p0, p1, p2, p3);
            }
            rs += __shfl_xor(rs, 16);
            rs += __shfl_xor(rs, 32);
            l_t += rs;
        }

        __builtin_amdgcn_s_setprio(1);
#pragma unroll
        for (int dt = 0; dt < 4; ++dt) {
            const int d = dt*16 + lm;
            const int dw = d & 7;
#pragma unroll
            for (int ms = 0; ms < 4; ++ms) {
                bf16x4 vf = *(const bf16x4*)&VS[d*64 + ((2*ms + (lq>>1)) ^ dw)*8 + (lq&1)*4];
                O[dt] = MFMA16(P[ms], vf, O[dt]);
            }
        }
        __builtin_amdgcn_s_setprio(0);
        cur ^= 1;
    }

    {
        float inv = 1.0f / l_t;
        f32x4 iv;
#pragma unroll
        for (int r = 0; r < 4; ++r) iv[r] = __shfl(inv, lq*4 + r);
        int tbase = t0 + w*16;
        if (lq == 0) {
            mbuf[(size_t)bh*T_LEN + tbase + lm] = m_t;
            lbuf[(size_t)bh*T_LEN + tbase + lm] = l_t;
        }
#pragma unroll
        for (int dt = 0; dt < 4; ++dt)
#pragma unroll
            for (int r = 0; r < 4; ++r) {
                int t = tbase + lq*4 + r;
                float val = O[dt][r] * iv[r];
                u16 hv = f2bf(val);
                u16 lv = f2bf(val - bf2f(hv));
                size_t o = ((size_t)t*B_SZ + b)*EMB + hh*HD + dt*16 + lm;
                attnHi[o] = hv; attnLo[o] = lv;
            }
    }
}

// ---------------- avg weights: MFMA recompute S^T, apply saved (m,l) ---------
// Same dropped-K-lo 4-MFMA score (IDENTICAL term set & order as flash ->
// consistent with saved m,l). 512 thr = 8 waves x 16 t-rows; K-hi only,
// double-buffered across heads (32KB LDS -> 2 blocks/CU = 50% occupancy).
__global__ __launch_bounds__(512)
void avg_kernel(const u16* __restrict__ qHi, const u16* __restrict__ qLo,
                const u16* __restrict__ kHi,
                const float* __restrict__ mbuf, const float* __restrict__ lbuf,
                float* __restrict__ avg)
{
    __shared__ __align__(16) u16 Khi[2][128*64];
    const int tid = threadIdx.x;
    const int w = tid >> 6, ln = tid & 63, lm = ln & 15, lq = ln >> 4;
    const int s0 = blockIdx.x * 128;
    const int t0 = blockIdx.y * 128;
    const int b  = blockIdx.z;
    const int sr = ln >> 3, scc = ln & 7;
    f32x4 acc[8];
#pragma unroll
    for (int ms = 0; ms < 8; ++ms) acc[ms] = (f32x4){0.f,0.f,0.f,0.f};

    auto stage = [&](int p, int h) {
        const int bhh = b*HEADS + h;
#pragma unroll
        for (int i = 0; i < 2; ++i) {
            int ch = w*2 + i;            // 16 chunks over 8 waves
            int r = ch*8 + sr;
            int c = scc ^ (r & 7);
            lds_cp16(&Khi[p][ch*512], kHi + ((size_t)bhh*T_LEN + s0 + r)*HD + c*8);
        }
    };

    stage(0, 0);
    int cur = 0;
    const int t = t0 + w*16 + lm;
    for (int h = 0; h < HEADS; ++h) {
        const int bh = b*HEADS + h;
        // q/m/l loads issued BEFORE the barrier: latency overlaps the drain.
        bf16x8 qfh[2], qfl[2];
        size_t qo = ((size_t)bh*T_LEN + t)*HD;
#pragma unroll
        for (int f = 0; f < 2; ++f) {
            qfh[f] = *(const bf16x8*)(qHi + qo + f*32 + lq*8);
            qfl[f] = *(const bf16x8*)(qLo + qo + f*32 + lq*8);
        }
        float mv = mbuf[(size_t)bh*T_LEN + t];
        float lv = 1.0f / lbuf[(size_t)bh*T_LEN + t];
        __syncthreads();                       // buf[cur] staged + prev reads done
        if (h + 1 < HEADS) stage(cur ^ 1, h + 1);   // prefetch next head

        const u16* __restrict__ KH = Khi[cur];
#pragma unroll
        for (int ms = 0; ms < 8; ++ms) {
            const int kr = ms*16 + lm;
            const int sw = kr & 7;
            const u16* rowH = &KH[kr*64];
            bf16x8 ah0 = *(const bf16x8*)(rowH + ((lq    ) ^ sw)*8);
            bf16x8 ah1 = *(const bf16x8*)(rowH + ((lq + 4) ^ sw)*8);
            f32x4 s4 = {0.f,0.f,0.f,0.f};
            s4 = MFMA32(ah0, qfl[0], s4);
            s4 = MFMA32(ah1, qfl[1], s4);
            s4 = MFMA32(ah0, qfh[0], s4);
            s4 = MFMA32(ah1, qfh[1], s4);
            f32x4 a = acc[ms];
            a[0] += exp2f_fast(s4[0]-mv)*lv;
            a[1] += exp2f_fast(s4[1]-mv)*lv;
            a[2] += exp2f_fast(s4[2]-mv)*lv;
            a[3] += exp2f_fast(s4[3]-mv)*lv;
            acc[ms] = a;
        }
        cur ^= 1;
    }
    const float sc = 1.0f / HEADS;
#pragma unroll
    for (int ms = 0; ms < 8; ++ms) {
        float4 v;
        v.x = acc[ms][0]*sc; v.y = acc[ms][1]*sc;
        v.z = acc[ms][2]*sc; v.w = acc[ms][3]*sc;
        *(float4*)(avg + ((size_t)b*T_LEN + t)*T_LEN + s0 + ms*16 + lq*4) = v;
    }
}

extern "C" void kernel_launch(void* const* d_in, const int* in_sizes, int n_in,
                              void* d_out, int out_size, void* d_ws, size_t ws_size,
                              hipStream_t stream)
{
    const float* query = (const float*)d_in[0];
    const float* key   = (const float*)d_in[1];
    const float* value = (const float*)d_in[2];
    const float* Wq = (const float*)d_in[3];
    const float* bq = (const float*)d_in[4];
    const float* Wk = (const float*)d_in[5];
    const float* bk = (const float*)d_in[6];
    const float* Wv = (const float*)d_in[7];
    const float* bv = (const float*)d_in[8];
    const float* Wo = (const float*)d_in[9];
    const float* bo = (const float*)d_in[10];

    float* out = (float*)d_out;                  // [T,B,E]
    float* avg = out + (size_t)R_ROWS*EMB;       // [B,T,S]

    const size_t NX = (size_t)R_ROWS*EMB;        // 4194304
    const size_t NW = (size_t)EMB*EMB;           // 1048576
    u16* wsu = (u16*)d_ws;
    u16* cHi  = wsu;            u16* cLo  = cHi + NX;     // conv scratch; later attnHi/Lo
    u16* WqHi = cLo + NX;       u16* WqLo = WqHi + NW;
    u16* WkHi = WqLo + NW;      u16* WkLo = WkHi + NW;
    u16* WvHi = WkLo + NW;      u16* WvLo = WvHi + NW;
    u16* WoHi = WvLo + NW;      u16* WoLo = WoHi + NW;
    u16* qHi  = WoLo + NW;      u16* qLo  = qHi + NX;     // head-major [bh][t][d]
    u16* kHi  = qLo + NX;       u16* kLo  = kHi + NX;     // kLo slot unused now
    u16* vT   = kLo + NX;                                  // [bh][d][t]
    float* mb = (float*)(vT + NX);
    float* lb = mb + (size_t)BH*T_LEN;

    // HEAD_DIM^-0.5 * log2(e): scores land in log2 domain -> bare v_exp_f32.
    const float qscale = 0.125f * 1.44269504088896340736f;

    // weight hi/lo splits
    conv_kernel<<<NW/2048, 256, 0, stream>>>(Wq, WqHi, WqLo);
    conv_kernel<<<NW/2048, 256, 0, stream>>>(Wk, WkHi, WkLo);
    conv_kernel<<<NW/2048, 256, 0, stream>>>(Wv, WvHi, WvLo);
    conv_kernel<<<NW/2048, 256, 0, stream>>>(Wo, WoHi, WoLo);

    dim3 gP(R_ROWS/128, EMB/64);       // (32,16) modes 0/1
    dim3 gPv(EMB/128, R_ROWS/64);      // (8,64)  mode 2

    conv_kernel<<<NX/2048, 256, 0, stream>>>(query, cHi, cLo);
    proj_mfma<<<gP, 512, 0, stream>>>(cHi, cLo, WqHi, WqLo, bq, nullptr, qHi, qLo, qscale, 1);
    conv_kernel<<<NX/2048, 256, 0, stream>>>(key, cHi, cLo);
    proj_mfma<<<gP, 512, 0, stream>>>(cHi, cLo, WkHi, WkLo, bk, nullptr, kHi, nullptr, 1.0f, 1);
    conv_kernel<<<NX/2048, 256, 0, stream>>>(value, cHi, cLo);
    proj_mfma<<<gPv, 512, 0, stream>>>(WvHi, WvLo, cHi, cLo, bv, nullptr, vT, nullptr, 1.0f, 2);

    flash_kernel<<<dim3(T_LEN/64, BH), 256, 0, stream>>>(qHi, qLo, kHi, vT,
                                                         cHi, cLo, mb, lb);
    proj_mfma<<<gP, 512, 0, stream>>>(cHi, cLo, WoHi, WoLo, bo, out, nullptr, nullptr, 1.0f, 0);
    avg_kernel<<<dim3(T_LEN/128, T_LEN/128, B_SZ), 512, 0, stream>>>(qHi, qLo, kHi, mb, lb, avg);
}